// Round 20
// baseline (228.133 us; speedup 1.0000x reference)
//
#include <hip/hip_runtime.h>
#include <cstdint>
#include <cstddef>

#define N_NODES 100000
#define E_EDGES 1600000
#define E_TOT   1700000
#define HEADS   8
#define C1      8
#define HC1     64
#define NCLS    3
#define HC2     24
#define IN_CH   500
#define NEG     0.2f

#define TILES   6250    /* 100000 / 16 */
#define GBLK    512     /* gemm1 grid: 2 blocks/CU (LDS 40KB, VGPR<=128) */

#define NPB     391     /* nodes per bucket */
#define NBUCK   256     /* 256*391 = 100096 >= N */
#define CHUNK   4096    /* edges per chunk block */
#define NCHUNK  416     /* ceil(1700000/4096) */
#define SCAP    8192    /* partB LDS stage capacity (mean 6641, ~19 sigma) */

typedef __attribute__((ext_vector_type(8))) _Float16 f16x8;
typedef __attribute__((ext_vector_type(4))) _Float16 f16x4;
typedef __attribute__((ext_vector_type(4))) float f32x4;

__device__ __forceinline__ int edge_at(const int* __restrict__ ei, int idx, int mode) {
  return mode ? ei[idx] : ei[2 * idx];   // int64: low word
}

// Block-local int32/int64 detection from a FIXED window (first 4096 odd int32
// words of ei). Same window for every block -> consistent, deterministic.
__device__ __forceinline__ int detect_mode(const int* __restrict__ ei,
                                           int tid, int* shflag) {
  if (tid == 0) *shflag = 0;
  __syncthreads();
  int nz = 0;
#pragma unroll
  for (int i = 0; i < 16; ++i) nz |= ei[2 * (i * 256 + tid) + 1];
  if (__ballot(nz != 0)) {
    if ((tid & 63) == 0) atomicOr(shflag, 1);
  }
  __syncthreads();
  return *shflag;
}

// ---------------- CSR build: deterministic 3-pass counting sort --------------
// ZERO global atomics; positions exact -> tripwire-stable (R12-R19 proven).

__global__ __launch_bounds__(256) void k_cntA(const int* __restrict__ ei,
    int* __restrict__ cmat, const float* __restrict__ W1l,
    const float* __restrict__ W1r, _Float16* __restrict__ Wimg) {
  __shared__ int cnt[NBUCK];
  __shared__ int shflag;
  const int tid = threadIdx.x;

  if (blockIdx.x >= NCHUNK) {          // fused W1 pre-convert (independent)
    int b2 = blockIdx.x - NCHUNK;
    int t = b2 * 256 + tid;            // 65536 = 128*512
    int col = t >> 9, k = t & 511;
    float v = 0.f;
    if (k < IN_CH) v = (col < HC1) ? W1l[k * HC1 + col] : W1r[k * HC1 + (col - HC1)];
    int boff = (col * 1024 + k * 2) ^ ((col & 7) << 4);
    Wimg[boff >> 1] = (_Float16)v;
    return;
  }

  const int mode = detect_mode(ei, tid, &shflag);
  const int e0 = blockIdx.x * CHUNK;
  cnt[tid] = 0;
  __syncthreads();
#pragma unroll
  for (int i = 0; i < 16; ++i) {
    int e = e0 + i * 256 + tid;
    if (e < E_TOT) {
      int d = (e < E_EDGES) ? edge_at(ei, E_EDGES + e, mode) : (e - E_EDGES);
      atomicAdd(&cnt[d / NPB], 1);
    }
  }
  __syncthreads();
  cmat[blockIdx.x * NBUCK + tid] = cnt[tid];
}

__global__ void k_scanA(int* __restrict__ cmat, int* __restrict__ bbase,
                        int* __restrict__ rowptr) {
  __shared__ int sh[NBUCK];
  int b = threadIdx.x;
  int run = 0;
  for (int c = 0; c < NCHUNK; ++c) {
    int v = cmat[c * NBUCK + b];
    cmat[c * NBUCK + b] = run;
    run += v;
  }
  // Hillis-Steele inclusive scan of per-bucket totals
  int tot = run;
  sh[b] = tot;
  __syncthreads();
  for (int off = 1; off < NBUCK; off <<= 1) {
    int add = (b >= off) ? sh[b - off] : 0;
    __syncthreads();
    sh[b] += add;
    __syncthreads();
  }
  bbase[b] = sh[b] - tot;              // exclusive
  if (b == NBUCK - 1) {
    bbase[NBUCK] = sh[b];              // == E_TOT
    rowptr[N_NODES] = sh[b];
  }
}

__global__ __launch_bounds__(256) void k_grpA(const int* __restrict__ ei,
    const int* __restrict__ cmat, const int* __restrict__ bbase,
    unsigned* __restrict__ bstage) {
  __shared__ int cnt[NBUCK], ofs[NBUCK], cur[NBUCK], gbase[NBUCK];
  __shared__ unsigned buf[CHUNK];      // 16 KB
  __shared__ int shflag;
  const int tid = threadIdx.x;
  const int e0 = blockIdx.x * CHUNK;
  const int mode = detect_mode(ei, tid, &shflag);
  cnt[tid] = 0;
  __syncthreads();

  unsigned pk[16]; int bk[16];
#pragma unroll
  for (int i = 0; i < 16; ++i) {
    int e = e0 + i * 256 + tid;
    bk[i] = -1;
    if (e < E_TOT) {
      int s, d;
      if (e < E_EDGES) { s = edge_at(ei, e, mode); d = edge_at(ei, E_EDGES + e, mode); }
      else             { s = e - E_EDGES; d = s; }
      int b = d / NPB;
      bk[i] = b;
      pk[i] = ((unsigned)s << 9) | (unsigned)(d - b * NPB);
      atomicAdd(&cnt[b], 1);
    }
  }
  __syncthreads();
  // Hillis-Steele scan cnt -> ofs (exclusive), in-place double-barrier
  ofs[tid] = cnt[tid];
  __syncthreads();
  for (int off = 1; off < NBUCK; off <<= 1) {
    int add = (tid >= off) ? ofs[tid - off] : 0;
    __syncthreads();
    ofs[tid] += add;
    __syncthreads();
  }
  ofs[tid] -= cnt[tid];                // exclusive; own-index only
  cur[tid] = ofs[tid];
  gbase[tid] = bbase[tid] + cmat[blockIdx.x * NBUCK + tid];
  __syncthreads();
#pragma unroll
  for (int i = 0; i < 16; ++i) {
    if (bk[i] >= 0) {
      int slot = atomicAdd(&cur[bk[i]], 1);
      buf[slot] = pk[i];
    }
  }
  __syncthreads();
  const int n = cnt[tid], s0 = ofs[tid], g = gbase[tid];
  for (int j = 0; j < n; ++j) {
    int gp = g + j;
    if ((unsigned)gp < (unsigned)E_TOT) bstage[gp] = buf[s0 + j];
  }
}

__global__ __launch_bounds__(256) void k_partB(const unsigned* __restrict__ bstage,
    const int* __restrict__ bbase, int* __restrict__ rowptr, int* __restrict__ esrc) {
  __shared__ unsigned edges[SCAP];     // 32 KB
  __shared__ int lhist[NPB + 1];
  __shared__ int lptr[NPB];
  __shared__ int sh[256];
  const int b = blockIdx.x;
  const int tid = threadIdx.x;
  const int base = bbase[b];
  const int n = min(bbase[b + 1] - base, SCAP);
  const int nl = min(NPB, N_NODES - b * NPB);   // 391, or 295 for last bucket

  for (int k = tid; k < NPB; k += 256) lhist[k] = 0;
  for (int i = tid; i < n; i += 256) edges[i] = bstage[base + i];
  __syncthreads();
  for (int i = tid; i < n; i += 256) atomicAdd(&lhist[(int)(edges[i] & 511u)], 1);
  __syncthreads();
  // 2-elem/thread block scan: lhist -> lptr (excl+base)
  int i0 = tid * 2;
  int v0 = (i0 < nl) ? lhist[i0] : 0;
  int v1 = (i0 + 1 < nl) ? lhist[i0 + 1] : 0;
  int tsum = v0 + v1;
  sh[tid] = tsum;
  __syncthreads();
  for (int off = 1; off < 256; off <<= 1) {
    int add = (tid >= off) ? sh[tid - off] : 0;
    __syncthreads();
    sh[tid] += add;
    __syncthreads();
  }
  int run = base + sh[tid] - tsum;     // exclusive prefix for this pair
  if (i0 < nl)     lptr[i0] = run;
  if (i0 + 1 < nl) lptr[i0 + 1] = run + v0;
  __syncthreads();
  for (int k = tid; k < nl; k += 256) rowptr[b * NPB + k] = lptr[k];
  __syncthreads();                     // rowptr snapshot BEFORE lptr mutates
  for (int i = tid; i < n; i += 256) {
    unsigned pkv = edges[i];
    int pos = atomicAdd(&lptr[(int)(pkv & 511u)], 1);
    if ((unsigned)pos < (unsigned)E_TOT) esrc[pos] = (int)(pkv >> 9);
  }
}

// ---------------- GEMM1: fp16 2-product MFMA, B in registers, 2 blocks/CU ----
// R19->R20: LDS is 40KB and VGPR fits <=128, so run TWO co-resident blocks
// per CU (launch_bounds(512,4), grid 512). A partner block fills the sync
// drains and x-prefetch bubbles that were exposed at 1 block/CU.
#define ALO   16384
#define PBASE 32768

__global__ __launch_bounds__(512, 4) void k_gemm1(const float* __restrict__ x,
    const _Float16* __restrict__ Wimg, _Float16* __restrict__ xlh,
    float* __restrict__ xr) {
  __shared__ char lds[40960];          // A hi [0,16K) + A lo [16K,32K) + P [32K,40K)
  const int tid  = threadIdx.x;
  const int lane = tid & 63, wid = tid >> 6;
  const int lrow = lane & 15, kg = lane >> 4;
  const int colgrp = wid & 3;
  const int kw0 = (wid >> 2) * 8;

  // ---- B fragments: 2 cols x 8 kw, read once via the same swizzled offsets
  f16x8 bf[2][8];
#pragma unroll
  for (int n = 0; n < 2; ++n) {
    int col = colgrp * 32 + n * 16 + lrow;
#pragma unroll
    for (int kw = 0; kw < 8; ++kw) {
      int koff = (kw0 + kw) * 64 + kg * 16;
      int bo = (col * 1024 + koff) ^ ((col & 7) << 4);
      bf[n][kw] = *(const f16x8*)((const char*)Wimg + bo);
    }
  }

  int xoff[4], aoff[4], mode[4];
#pragma unroll
  for (int i = 0; i < 4; ++i) {
    int s = tid + i * 512;
    if (s < 2000) {
      int row = s / 125, c4 = s - row * 125;
      xoff[i] = row * 500 + c4 * 4;
      aoff[i] = (row * 1024 + c4 * 8) ^ ((row & 7) << 4);
      mode[i] = 0;
    } else {
      int p = s - 2000;           // 0..47
      int row = p / 3, j = p - row * 3;
      aoff[i] = (row * 1024 + 1000 + j * 8) ^ ((row & 7) << 4);
      xoff[i] = 0;
      mode[i] = 1;
    }
  }

  float4 rv[4];
  auto loadregs = [&](int tile) {
#pragma unroll
    for (int i = 0; i < 4; ++i)
      if (mode[i] == 0)
        rv[i] = *(const float4*)&x[(size_t)tile * 8000 + xoff[i]];
  };

  if (blockIdx.x < TILES) loadregs(blockIdx.x);

  for (int tile = blockIdx.x; tile < TILES; tile += GBLK) {
    // ---- stage A: convert fp32 regs -> fp16 hi + (lo * 2048), swizzled LDS
#pragma unroll
    for (int i = 0; i < 4; ++i) {
      f16x4 h, l;
      if (mode[i] == 0) {
        float vals[4] = {rv[i].x, rv[i].y, rv[i].z, rv[i].w};
#pragma unroll
        for (int c = 0; c < 4; ++c) {
          _Float16 hh = (_Float16)vals[c];
          float r = vals[c] - (float)hh;
          h[c] = hh;
          l[c] = (_Float16)(r * 2048.f);
        }
      } else {
        h = (f16x4){0, 0, 0, 0}; l = (f16x4){0, 0, 0, 0};
      }
      *(f16x4*)(lds + aoff[i]) = h;
      *(f16x4*)(lds + ALO + aoff[i]) = l;
    }
    __syncthreads();   // sync_a: A(t) visible (orders prev combine before publish)
    if (tile + GBLK < TILES) loadregs(tile + GBLK);   // prefetch under compute

    f32x4 acch[2], accl[2];
    acch[0] = (f32x4){0,0,0,0}; acch[1] = (f32x4){0,0,0,0};
    accl[0] = (f32x4){0,0,0,0}; accl[1] = (f32x4){0,0,0,0};
#pragma unroll
    for (int kw = 0; kw < 8; ++kw) {
      const int koff = (kw0 + kw) * 64 + kg * 16;
      int ao = (lrow * 1024 + koff) ^ ((lrow & 7) << 4);
      f16x8 ah = *(const f16x8*)(lds + ao);
      f16x8 al = *(const f16x8*)(lds + ALO + ao);
#pragma unroll
      for (int n = 0; n < 2; ++n) {
        acch[n] = __builtin_amdgcn_mfma_f32_16x16x32_f16(ah, bf[n][kw], acch[n], 0, 0, 0);
        accl[n] = __builtin_amdgcn_mfma_f32_16x16x32_f16(al, bf[n][kw], accl[n], 0, 0, 0);
      }
    }
    float v[2][4];
#pragma unroll
    for (int n = 0; n < 2; ++n)
#pragma unroll
      for (int j = 0; j < 4; ++j)
        v[n][j] = acch[n][j] + accl[n][j] * 4.8828125e-4f;

    if (wid >= 4) {   // upper K-half: publish partials into dedicated P region
      char* p = lds + PBASE + ((wid - 4) * 64 + lane) * 32;
      *(float4*)p       = make_float4(v[0][0], v[0][1], v[0][2], v[0][3]);
      *(float4*)(p+16)  = make_float4(v[1][0], v[1][1], v[1][2], v[1][3]);
    }
    __syncthreads();  // sync_b: P visible; all A(t) reads drained
    if (wid < 4) {    // lower K-half: combine + store C (overlaps next staging)
      const char* p = lds + PBASE + (wid * 64 + lane) * 32;
      float4 p0 = *(const float4*)p, p1 = *(const float4*)(p+16);
      v[0][0]+=p0.x; v[0][1]+=p0.y; v[0][2]+=p0.z; v[0][3]+=p0.w;
      v[1][0]+=p1.x; v[1][1]+=p1.y; v[1][2]+=p1.z; v[1][3]+=p1.w;
      const int bm0 = tile * 16;
      if (colgrp < 2) {         // xl -> fp16
#pragma unroll
        for (int n = 0; n < 2; ++n) {
          int cc = colgrp * 32 + n * 16 + lrow;
#pragma unroll
          for (int j = 0; j < 4; ++j)
            xlh[(size_t)(bm0 + kg * 4 + j) * HC1 + cc] = (_Float16)v[n][j];
        }
      } else {                  // xr -> fp32
#pragma unroll
        for (int n = 0; n < 2; ++n) {
          int cc = (colgrp - 2) * 32 + n * 16 + lrow;
#pragma unroll
          for (int j = 0; j < 4; ++j)
            xr[(size_t)(bm0 + kg * 4 + j) * HC1 + cc] = v[n][j];
        }
      }
    }
  }
}

// ---------------- FUSED layer-1 edge pass + GEMM2 (R19-proven) ---------------
__global__ __launch_bounds__(256) void k_edge1g2(const _Float16* __restrict__ xl1h,
    const float* __restrict__ xr1, const float* __restrict__ att1,
    const float* __restrict__ b1, const float* __restrict__ W2l,
    const float* __restrict__ W2r, const int* __restrict__ rowptr,
    const int* __restrict__ esrc, _Float16* __restrict__ xl2p,
    float* __restrict__ xr2) {
  __shared__ float w[64][48];       // 12 KB
  __shared__ float hsh[32][65];     // 8.3 KB (+1 pad: stride-64 bank fix)
  __shared__ float out48[32][49];   // 6.3 KB (+1 pad)
  const int tid = threadIdx.x;

  for (int i = tid; i < 64 * 48; i += 256) {
    int k = i / 48, j = i - k * 48;
    w[k][j] = (j < HC2) ? W2l[k * HC2 + j] : W2r[k * HC2 + (j - HC2)];
  }

  // ---- phase 1: online segment softmax (identical math to R18 edge1)
  int t = blockIdx.x * 256 + tid;   // exact grid: N/32 blocks
  int node = t >> 3, h = t & 7;
  const float4* xrp = (const float4*)(xr1 + (size_t)node * HC1 + h * C1);
  float4 xa = xrp[0], xb = xrp[1];
  float xrv[8] = {xa.x, xa.y, xa.z, xa.w, xb.x, xb.y, xb.z, xb.w};
  const float4* ap = (const float4*)(att1 + h * C1);
  float4 aa = ap[0], ab = ap[1];
  float av[8] = {aa.x, aa.y, aa.z, aa.w, ab.x, ab.y, ab.z, ab.w};

  float m = -INFINITY, s = 0.f;
  float acc[8];
#pragma unroll
  for (int c = 0; c < 8; ++c) acc[c] = 0.f;

  auto gather = [&](int sn, float* v) {
    f16x8 q = *(const f16x8*)(xl1h + (size_t)sn * HC1 + h * C1);  // 16B
#pragma unroll
    for (int c = 0; c < 8; ++c) v[c] = (float)q[c];
  };
  auto process = [&](const float* v) {
    float logit = 0.f;
#pragma unroll
    for (int c = 0; c < 8; ++c) {
      float u = v[c] + xrv[c];
      u = (u > 0.f) ? u : NEG * u;
      logit = fmaf(u, av[c], logit);
    }
    float mn = fmaxf(m, logit);
    float so = __expf(m - mn);
    float p  = __expf(logit - mn);
    s = s * so + p;
#pragma unroll
    for (int c = 0; c < 8; ++c) acc[c] = fmaf(acc[c], so, p * v[c]);
    m = mn;
  };

  int beg = rowptr[node], end = rowptr[node + 1];
  int i = beg;
  for (; i + 1 < end; i += 2) {
    int sn0 = esrc[i], sn1 = esrc[i + 1];
    if ((unsigned)sn0 >= N_NODES) sn0 = node;   // defensive: never OOB
    if ((unsigned)sn1 >= N_NODES) sn1 = node;
    float v0[8], v1[8];
    gather(sn0, v0); gather(sn1, v1);
    process(v0); process(v1);
  }
  if (i < end) {
    int sn0 = esrc[i];
    if ((unsigned)sn0 >= N_NODES) sn0 = node;
    float v0[8]; gather(sn0, v0); process(v0);
  }

  float inv = (s > 0.f) ? 1.f / s : 0.f;        // defensive: no 0/0 NaN
  const int ln = tid >> 3;
#pragma unroll
  for (int c = 0; c < 8; ++c) {
    float v = fmaf(acc[c], inv, b1[h * C1 + c]);
    v = (v > 0.f) ? v : expm1f(v);    // ELU
    hsh[ln][h * 8 + c] = v;           // fp32 (no fp16 round-trip)
  }
  __syncthreads();                    // h ready + W2 staged

  // ---- phase 2: (ln, g) computes outputs g*6..g*6+5 of the 48-wide GEMM
  const int g = tid & 7;
  float a6[6] = {0.f, 0.f, 0.f, 0.f, 0.f, 0.f};
#pragma unroll 4
  for (int k = 0; k < 64; ++k) {
    float hv = hsh[ln][k];
    const float* wr = &w[k][g * 6];
#pragma unroll
    for (int j = 0; j < 6; ++j) a6[j] = fmaf(hv, wr[j], a6[j]);
  }
#pragma unroll
  for (int j = 0; j < 6; ++j) out48[ln][g * 6 + j] = a6[j];
  __syncthreads();

  // ---- repack: lane h packs node ln's head-h outputs
  const int gnode = blockIdx.x * 32 + ln;
  f16x4 hx;
#pragma unroll
  for (int c = 0; c < 3; ++c) hx[c] = (_Float16)out48[ln][h * 3 + c];
  hx[3] = (_Float16)0.f;
  *(f16x4*)(xl2p + (size_t)gnode * 32 + h * 4) = hx;
#pragma unroll
  for (int c = 0; c < 3; ++c)
    xr2[(size_t)gnode * HC2 + h * 3 + c] = out48[ln][24 + h * 3 + c];
}

// ---------------- layer-2 edge pass + head-mean + final softmax --------------
__global__ __launch_bounds__(256) void k_edge2(const _Float16* __restrict__ xl2p,
    const float* __restrict__ xr2, const float* __restrict__ att2,
    const float* __restrict__ b2, const int* __restrict__ rowptr,
    const int* __restrict__ esrc, float* __restrict__ out) {
  int t = blockIdx.x * blockDim.x + threadIdx.x;   // exact grid: N*8
  int node = t >> 3, h = t & 7;
  float xrv[3], av[3];
#pragma unroll
  for (int c = 0; c < 3; ++c) {
    xrv[c] = xr2[(size_t)node * HC2 + h * NCLS + c];
    av[c]  = att2[h * NCLS + c];
  }
  float m = -INFINITY, s = 0.f;
  float acc[3] = {0.f, 0.f, 0.f};

  auto process = [&](const float* v) {
    float logit = 0.f;
#pragma unroll
    for (int c = 0; c < 3; ++c) {
      float u = v[c] + xrv[c];
      u = (u > 0.f) ? u : NEG * u;
      logit = fmaf(u, av[c], logit);
    }
    float mn = fmaxf(m, logit);
    float so = __expf(m - mn);
    float p  = __expf(logit - mn);
    s = s * so + p;
#pragma unroll
    for (int c = 0; c < 3; ++c) acc[c] = fmaf(acc[c], so, p * v[c]);
    m = mn;
  };

  int beg = rowptr[node], end = rowptr[node + 1];
  int i = beg;
  for (; i + 1 < end; i += 2) {
    int sn0 = esrc[i], sn1 = esrc[i + 1];
    if ((unsigned)sn0 >= N_NODES) sn0 = node;
    if ((unsigned)sn1 >= N_NODES) sn1 = node;
    f16x4 q0 = *(const f16x4*)(xl2p + (size_t)sn0 * 32 + h * 4);  // 8B
    f16x4 q1 = *(const f16x4*)(xl2p + (size_t)sn1 * 32 + h * 4);
    float v0[3] = {(float)q0[0], (float)q0[1], (float)q0[2]};
    float v1[3] = {(float)q1[0], (float)q1[1], (float)q1[2]};
    process(v0); process(v1);
  }
  if (i < end) {
    int sn0 = esrc[i];
    if ((unsigned)sn0 >= N_NODES) sn0 = node;
    f16x4 q0 = *(const f16x4*)(xl2p + (size_t)sn0 * 32 + h * 4);
    float v0[3] = {(float)q0[0], (float)q0[1], (float)q0[2]};
    process(v0);
  }

  float inv = (s > 0.f) ? 1.f / s : 0.f;
  float o[3];
#pragma unroll
  for (int c = 0; c < 3; ++c) o[c] = acc[c] * inv;
  // mean over 8 heads (8-lane group butterfly; grid exact so all lanes live)
#pragma unroll
  for (int off = 1; off < 8; off <<= 1) {
#pragma unroll
    for (int c = 0; c < 3; ++c) o[c] += __shfl_xor(o[c], off);
  }
  if (h < 3) {
    float z[3];
#pragma unroll
    for (int c = 0; c < 3; ++c) z[c] = o[c] * 0.125f + b2[c];
    float mx = fmaxf(fmaxf(z[0], z[1]), z[2]);
    float e0 = __expf(z[0] - mx), e1 = __expf(z[1] - mx), e2 = __expf(z[2] - mx);
    float sum = e0 + e1 + e2;
    float num = (h == 0) ? e0 : (h == 1) ? e1 : e2;
    out[(size_t)node * NCLS + h] = num / sum;
  }
}

// ---------------- launch -----------------------------------------------------
extern "C" void kernel_launch(void* const* d_in, const int* in_sizes, int n_in,
                              void* d_out, int out_size, void* d_ws, size_t ws_size,
                              hipStream_t stream) {
  (void)in_sizes; (void)n_in; (void)out_size; (void)ws_size;
  const float* x    = (const float*)d_in[0];
  const int*   ei   = (const int*)d_in[1];
  const float* W1l  = (const float*)d_in[2];
  const float* W1r  = (const float*)d_in[3];
  const float* att1 = (const float*)d_in[4];
  const float* b1   = (const float*)d_in[5];
  const float* W2l  = (const float*)d_in[6];
  const float* W2r  = (const float*)d_in[7];
  const float* att2 = (const float*)d_in[8];
  const float* b2   = (const float*)d_in[9];
  float* out = (float*)d_out;

  char* w = (char*)d_ws;
  _Float16* xl1h  = (_Float16*)(w);            // 12.8 MB (bstage overlays pre-gemm1)
  float* xr1      = (float*)(w + 12800000);    // 25.6 MB -> ends 38.4M
  _Float16* xl2p  = (_Float16*)(w + 38400000); // 6.4 MB  (disjoint from xl1h!)
  float* xr2      = (float*)(w + 44800000);    // 9.6 MB -> ends 54.4M
  _Float16* Wimg  = (_Float16*)(w + 64000000); // 128 KB
  unsigned* bstage = (unsigned*)(w);           // 6.8 MB, dead before gemm1
  char* ip = w + 76800000;
  int* rowptr = (int*)(ip);                    // 400,004 B
  int* cmat   = (int*)(ip + 400128);           // 425,984 B
  int* bbase  = (int*)(ip + 826112);           // 1,028 B
  int* esrc   = (int*)(ip + 827648);           // 6.8 MB

  k_cntA    <<<NCHUNK + 256, 256, 0, stream>>>(ei, cmat, W1l, W1r, Wimg);
  k_scanA   <<<1, NBUCK, 0, stream>>>(cmat, bbase, rowptr);
  k_grpA    <<<NCHUNK, 256, 0, stream>>>(ei, cmat, bbase, bstage);
  k_partB   <<<NBUCK, 256, 0, stream>>>(bstage, bbase, rowptr, esrc);
  k_gemm1   <<<GBLK, 512, 0, stream>>>(x, Wimg, xl1h, xr1);
  k_edge1g2 <<<N_NODES / 32, 256, 0, stream>>>(xl1h, xr1, att1, b1, W2l, W2r,
                                               rowptr, esrc, xl2p, xr2);
  k_edge2   <<<(N_NODES * HEADS) / 256, 256, 0, stream>>>(xl2p, xr2, att2, b2, rowptr, esrc, out);
}

// Round 21
// 219.402 us; speedup vs baseline: 1.0398x; 1.0398x over previous
//
#include <hip/hip_runtime.h>
#include <cstdint>
#include <cstddef>

#define N_NODES 100000
#define E_EDGES 1600000
#define E_TOT   1700000
#define HEADS   8
#define C1      8
#define HC1     64
#define NCLS    3
#define HC2     24
#define IN_CH   500
#define NEG     0.2f

#define TILES   6250    /* 100000 / 16 */
#define NBLK    256

#define NPB     391     /* nodes per bucket */
#define NBUCK   256     /* 256*391 = 100096 >= N */
#define CHUNK   4096    /* edges per chunk block */
#define NCHUNK  416     /* ceil(1700000/4096) */
#define SCAP    8192    /* partB LDS stage capacity (mean 6641, ~19 sigma) */

typedef __attribute__((ext_vector_type(8))) _Float16 f16x8;
typedef __attribute__((ext_vector_type(4))) _Float16 f16x4;
typedef __attribute__((ext_vector_type(4))) float f32x4;

__device__ __forceinline__ int edge_at(const int* __restrict__ ei, int idx, int mode) {
  return mode ? ei[idx] : ei[2 * idx];   // int64: low word
}

// Block-local int32/int64 detection from a FIXED window (first 4096 odd int32
// words of ei). Same window for every block -> consistent, deterministic.
__device__ __forceinline__ int detect_mode(const int* __restrict__ ei,
                                           int tid, int* shflag) {
  if (tid == 0) *shflag = 0;
  __syncthreads();
  int nz = 0;
#pragma unroll
  for (int i = 0; i < 16; ++i) nz |= ei[2 * (i * 256 + tid) + 1];
  if (__ballot(nz != 0)) {
    if ((tid & 63) == 0) atomicOr(shflag, 1);
  }
  __syncthreads();
  return *shflag;
}

// ---------------- CSR build: deterministic 3-pass counting sort --------------
// ZERO global atomics; positions exact -> tripwire-stable (R12-R19 proven).

__global__ __launch_bounds__(256) void k_cntA(const int* __restrict__ ei,
    int* __restrict__ cmat, const float* __restrict__ W1l,
    const float* __restrict__ W1r, _Float16* __restrict__ Wimg) {
  __shared__ int cnt[NBUCK];
  __shared__ int shflag;
  const int tid = threadIdx.x;

  if (blockIdx.x >= NCHUNK) {          // fused W1 pre-convert (independent)
    int b2 = blockIdx.x - NCHUNK;
    int t = b2 * 256 + tid;            // 65536 = 128*512
    int col = t >> 9, k = t & 511;
    float v = 0.f;
    if (k < IN_CH) v = (col < HC1) ? W1l[k * HC1 + col] : W1r[k * HC1 + (col - HC1)];
    int boff = (col * 1024 + k * 2) ^ ((col & 7) << 4);
    Wimg[boff >> 1] = (_Float16)v;
    return;
  }

  const int mode = detect_mode(ei, tid, &shflag);
  const int e0 = blockIdx.x * CHUNK;
  cnt[tid] = 0;
  __syncthreads();
#pragma unroll
  for (int i = 0; i < 16; ++i) {
    int e = e0 + i * 256 + tid;
    if (e < E_TOT) {
      int d = (e < E_EDGES) ? edge_at(ei, E_EDGES + e, mode) : (e - E_EDGES);
      atomicAdd(&cnt[d / NPB], 1);
    }
  }
  __syncthreads();
  cmat[blockIdx.x * NBUCK + tid] = cnt[tid];
}

__global__ void k_scanA(int* __restrict__ cmat, int* __restrict__ bbase,
                        int* __restrict__ rowptr) {
  __shared__ int sh[NBUCK];
  int b = threadIdx.x;
  int run = 0;
  for (int c = 0; c < NCHUNK; ++c) {
    int v = cmat[c * NBUCK + b];
    cmat[c * NBUCK + b] = run;
    run += v;
  }
  // Hillis-Steele inclusive scan of per-bucket totals
  int tot = run;
  sh[b] = tot;
  __syncthreads();
  for (int off = 1; off < NBUCK; off <<= 1) {
    int add = (b >= off) ? sh[b - off] : 0;
    __syncthreads();
    sh[b] += add;
    __syncthreads();
  }
  bbase[b] = sh[b] - tot;              // exclusive
  if (b == NBUCK - 1) {
    bbase[NBUCK] = sh[b];              // == E_TOT
    rowptr[N_NODES] = sh[b];
  }
}

__global__ __launch_bounds__(256) void k_grpA(const int* __restrict__ ei,
    const int* __restrict__ cmat, const int* __restrict__ bbase,
    unsigned* __restrict__ bstage) {
  __shared__ int cnt[NBUCK], ofs[NBUCK], cur[NBUCK], gbase[NBUCK];
  __shared__ unsigned buf[CHUNK];      // 16 KB
  __shared__ int shflag;
  const int tid = threadIdx.x;
  const int e0 = blockIdx.x * CHUNK;
  const int mode = detect_mode(ei, tid, &shflag);
  cnt[tid] = 0;
  __syncthreads();

  unsigned pk[16]; int bk[16];
#pragma unroll
  for (int i = 0; i < 16; ++i) {
    int e = e0 + i * 256 + tid;
    bk[i] = -1;
    if (e < E_TOT) {
      int s, d;
      if (e < E_EDGES) { s = edge_at(ei, e, mode); d = edge_at(ei, E_EDGES + e, mode); }
      else             { s = e - E_EDGES; d = s; }
      int b = d / NPB;
      bk[i] = b;
      pk[i] = ((unsigned)s << 9) | (unsigned)(d - b * NPB);
      atomicAdd(&cnt[b], 1);
    }
  }
  __syncthreads();
  // Hillis-Steele scan cnt -> ofs (exclusive), in-place double-barrier
  ofs[tid] = cnt[tid];
  __syncthreads();
  for (int off = 1; off < NBUCK; off <<= 1) {
    int add = (tid >= off) ? ofs[tid - off] : 0;
    __syncthreads();
    ofs[tid] += add;
    __syncthreads();
  }
  ofs[tid] -= cnt[tid];                // exclusive; own-index only
  cur[tid] = ofs[tid];
  gbase[tid] = bbase[tid] + cmat[blockIdx.x * NBUCK + tid];
  __syncthreads();
#pragma unroll
  for (int i = 0; i < 16; ++i) {
    if (bk[i] >= 0) {
      int slot = atomicAdd(&cur[bk[i]], 1);
      buf[slot] = pk[i];
    }
  }
  __syncthreads();
  const int n = cnt[tid], s0 = ofs[tid], g = gbase[tid];
  for (int j = 0; j < n; ++j) {
    int gp = g + j;
    if ((unsigned)gp < (unsigned)E_TOT) bstage[gp] = buf[s0 + j];
  }
}

__global__ __launch_bounds__(256) void k_partB(const unsigned* __restrict__ bstage,
    const int* __restrict__ bbase, int* __restrict__ rowptr, int* __restrict__ esrc) {
  __shared__ unsigned edges[SCAP];     // 32 KB
  __shared__ int lhist[NPB + 1];
  __shared__ int lptr[NPB];
  __shared__ int sh[256];
  const int b = blockIdx.x;
  const int tid = threadIdx.x;
  const int base = bbase[b];
  const int n = min(bbase[b + 1] - base, SCAP);
  const int nl = min(NPB, N_NODES - b * NPB);   // 391, or 295 for last bucket

  for (int k = tid; k < NPB; k += 256) lhist[k] = 0;
  for (int i = tid; i < n; i += 256) edges[i] = bstage[base + i];
  __syncthreads();
  for (int i = tid; i < n; i += 256) atomicAdd(&lhist[(int)(edges[i] & 511u)], 1);
  __syncthreads();
  // 2-elem/thread block scan: lhist -> lptr (excl+base)
  int i0 = tid * 2;
  int v0 = (i0 < nl) ? lhist[i0] : 0;
  int v1 = (i0 + 1 < nl) ? lhist[i0 + 1] : 0;
  int tsum = v0 + v1;
  sh[tid] = tsum;
  __syncthreads();
  for (int off = 1; off < 256; off <<= 1) {
    int add = (tid >= off) ? sh[tid - off] : 0;
    __syncthreads();
    sh[tid] += add;
    __syncthreads();
  }
  int run = base + sh[tid] - tsum;     // exclusive prefix for this pair
  if (i0 < nl)     lptr[i0] = run;
  if (i0 + 1 < nl) lptr[i0 + 1] = run + v0;
  __syncthreads();
  for (int k = tid; k < nl; k += 256) rowptr[b * NPB + k] = lptr[k];
  __syncthreads();                     // rowptr snapshot BEFORE lptr mutates
  for (int i = tid; i < n; i += 256) {
    unsigned pkv = edges[i];
    int pos = atomicAdd(&lptr[(int)(pkv & 511u)], 1);
    if ((unsigned)pos < (unsigned)E_TOT) esrc[pos] = (int)(pkv >> 9);
  }
}

// ---------------- GEMM1: fp16 2-product MFMA, B in registers (R19-best) ------
// R20 post-mortem: launch_bounds(512,4) forced 64 VGPR -> bf[] spilled to
// scratch (MfmaUtil 1.4%, 186us). Reverted to (512,1), grid 256 = measured
// best. gemm1 structural floor accepted (~56us vs ~32us compulsory x-read).
#define ALO   16384
#define PBASE 32768

__global__ __launch_bounds__(512, 1) void k_gemm1(const float* __restrict__ x,
    const _Float16* __restrict__ Wimg, _Float16* __restrict__ xlh,
    float* __restrict__ xr) {
  __shared__ char lds[40960];          // A hi [0,16K) + A lo [16K,32K) + P [32K,40K)
  const int tid  = threadIdx.x;
  const int lane = tid & 63, wid = tid >> 6;
  const int lrow = lane & 15, kg = lane >> 4;
  const int colgrp = wid & 3;
  const int kw0 = (wid >> 2) * 8;

  // ---- B fragments: 2 cols x 8 kw, read once via the same swizzled offsets
  f16x8 bf[2][8];
#pragma unroll
  for (int n = 0; n < 2; ++n) {
    int col = colgrp * 32 + n * 16 + lrow;
#pragma unroll
    for (int kw = 0; kw < 8; ++kw) {
      int koff = (kw0 + kw) * 64 + kg * 16;
      int bo = (col * 1024 + koff) ^ ((col & 7) << 4);
      bf[n][kw] = *(const f16x8*)((const char*)Wimg + bo);
    }
  }

  int xoff[4], aoff[4], mode[4];
#pragma unroll
  for (int i = 0; i < 4; ++i) {
    int s = tid + i * 512;
    if (s < 2000) {
      int row = s / 125, c4 = s - row * 125;
      xoff[i] = row * 500 + c4 * 4;
      aoff[i] = (row * 1024 + c4 * 8) ^ ((row & 7) << 4);
      mode[i] = 0;
    } else {
      int p = s - 2000;           // 0..47
      int row = p / 3, j = p - row * 3;
      aoff[i] = (row * 1024 + 1000 + j * 8) ^ ((row & 7) << 4);
      xoff[i] = 0;
      mode[i] = 1;
    }
  }

  float4 rv[4];
  auto loadregs = [&](int tile) {
#pragma unroll
    for (int i = 0; i < 4; ++i)
      if (mode[i] == 0)
        rv[i] = *(const float4*)&x[(size_t)tile * 8000 + xoff[i]];
  };

  loadregs(blockIdx.x);

  for (int tile = blockIdx.x; tile < TILES; tile += NBLK) {
    // ---- stage A: convert fp32 regs -> fp16 hi + (lo * 2048), swizzled LDS
#pragma unroll
    for (int i = 0; i < 4; ++i) {
      f16x4 h, l;
      if (mode[i] == 0) {
        float vals[4] = {rv[i].x, rv[i].y, rv[i].z, rv[i].w};
#pragma unroll
        for (int c = 0; c < 4; ++c) {
          _Float16 hh = (_Float16)vals[c];
          float r = vals[c] - (float)hh;
          h[c] = hh;
          l[c] = (_Float16)(r * 2048.f);
        }
      } else {
        h = (f16x4){0, 0, 0, 0}; l = (f16x4){0, 0, 0, 0};
      }
      *(f16x4*)(lds + aoff[i]) = h;
      *(f16x4*)(lds + ALO + aoff[i]) = l;
    }
    __syncthreads();   // sync_a: A(t) visible (orders prev combine before publish)
    if (tile + NBLK < TILES) loadregs(tile + NBLK);   // prefetch under compute

    f32x4 acch[2], accl[2];
    acch[0] = (f32x4){0,0,0,0}; acch[1] = (f32x4){0,0,0,0};
    accl[0] = (f32x4){0,0,0,0}; accl[1] = (f32x4){0,0,0,0};
#pragma unroll
    for (int kw = 0; kw < 8; ++kw) {
      const int koff = (kw0 + kw) * 64 + kg * 16;
      int ao = (lrow * 1024 + koff) ^ ((lrow & 7) << 4);
      f16x8 ah = *(const f16x8*)(lds + ao);
      f16x8 al = *(const f16x8*)(lds + ALO + ao);
#pragma unroll
      for (int n = 0; n < 2; ++n) {
        acch[n] = __builtin_amdgcn_mfma_f32_16x16x32_f16(ah, bf[n][kw], acch[n], 0, 0, 0);
        accl[n] = __builtin_amdgcn_mfma_f32_16x16x32_f16(al, bf[n][kw], accl[n], 0, 0, 0);
      }
    }
    float v[2][4];
#pragma unroll
    for (int n = 0; n < 2; ++n)
#pragma unroll
      for (int j = 0; j < 4; ++j)
        v[n][j] = acch[n][j] + accl[n][j] * 4.8828125e-4f;

    if (wid >= 4) {   // upper K-half: publish partials into dedicated P region
      char* p = lds + PBASE + ((wid - 4) * 64 + lane) * 32;
      *(float4*)p       = make_float4(v[0][0], v[0][1], v[0][2], v[0][3]);
      *(float4*)(p+16)  = make_float4(v[1][0], v[1][1], v[1][2], v[1][3]);
    }
    __syncthreads();  // sync_b: P visible; all A(t) reads drained
    if (wid < 4) {    // lower K-half: combine + store C (overlaps next staging)
      const char* p = lds + PBASE + (wid * 64 + lane) * 32;
      float4 p0 = *(const float4*)p, p1 = *(const float4*)(p+16);
      v[0][0]+=p0.x; v[0][1]+=p0.y; v[0][2]+=p0.z; v[0][3]+=p0.w;
      v[1][0]+=p1.x; v[1][1]+=p1.y; v[1][2]+=p1.z; v[1][3]+=p1.w;
      const int bm0 = tile * 16;
      if (colgrp < 2) {         // xl -> fp16
#pragma unroll
        for (int n = 0; n < 2; ++n) {
          int cc = colgrp * 32 + n * 16 + lrow;
#pragma unroll
          for (int j = 0; j < 4; ++j)
            xlh[(size_t)(bm0 + kg * 4 + j) * HC1 + cc] = (_Float16)v[n][j];
        }
      } else {                  // xr -> fp32
#pragma unroll
        for (int n = 0; n < 2; ++n) {
          int cc = (colgrp - 2) * 32 + n * 16 + lrow;
#pragma unroll
          for (int j = 0; j < 4; ++j)
            xr[(size_t)(bm0 + kg * 4 + j) * HC1 + cc] = v[n][j];
        }
      }
    }
  }
}

// ---------------- FUSED layer-1 edge pass + GEMM2 (R19-proven) ---------------
__global__ __launch_bounds__(256) void k_edge1g2(const _Float16* __restrict__ xl1h,
    const float* __restrict__ xr1, const float* __restrict__ att1,
    const float* __restrict__ b1, const float* __restrict__ W2l,
    const float* __restrict__ W2r, const int* __restrict__ rowptr,
    const int* __restrict__ esrc, _Float16* __restrict__ xl2p,
    float* __restrict__ xr2) {
  __shared__ float w[64][48];       // 12 KB
  __shared__ float hsh[32][65];     // 8.3 KB (+1 pad: stride-64 bank fix)
  __shared__ float out48[32][49];   // 6.3 KB (+1 pad)
  const int tid = threadIdx.x;

  for (int i = tid; i < 64 * 48; i += 256) {
    int k = i / 48, j = i - k * 48;
    w[k][j] = (j < HC2) ? W2l[k * HC2 + j] : W2r[k * HC2 + (j - HC2)];
  }

  // ---- phase 1: online segment softmax (identical math to R18 edge1)
  int t = blockIdx.x * 256 + tid;   // exact grid: N/32 blocks
  int node = t >> 3, h = t & 7;
  const float4* xrp = (const float4*)(xr1 + (size_t)node * HC1 + h * C1);
  float4 xa = xrp[0], xb = xrp[1];
  float xrv[8] = {xa.x, xa.y, xa.z, xa.w, xb.x, xb.y, xb.z, xb.w};
  const float4* ap = (const float4*)(att1 + h * C1);
  float4 aa = ap[0], ab = ap[1];
  float av[8] = {aa.x, aa.y, aa.z, aa.w, ab.x, ab.y, ab.z, ab.w};

  float m = -INFINITY, s = 0.f;
  float acc[8];
#pragma unroll
  for (int c = 0; c < 8; ++c) acc[c] = 0.f;

  auto gather = [&](int sn, float* v) {
    f16x8 q = *(const f16x8*)(xl1h + (size_t)sn * HC1 + h * C1);  // 16B
#pragma unroll
    for (int c = 0; c < 8; ++c) v[c] = (float)q[c];
  };
  auto process = [&](const float* v) {
    float logit = 0.f;
#pragma unroll
    for (int c = 0; c < 8; ++c) {
      float u = v[c] + xrv[c];
      u = (u > 0.f) ? u : NEG * u;
      logit = fmaf(u, av[c], logit);
    }
    float mn = fmaxf(m, logit);
    float so = __expf(m - mn);
    float p  = __expf(logit - mn);
    s = s * so + p;
#pragma unroll
    for (int c = 0; c < 8; ++c) acc[c] = fmaf(acc[c], so, p * v[c]);
    m = mn;
  };

  int beg = rowptr[node], end = rowptr[node + 1];
  int i = beg;
  for (; i + 1 < end; i += 2) {
    int sn0 = esrc[i], sn1 = esrc[i + 1];
    if ((unsigned)sn0 >= N_NODES) sn0 = node;   // defensive: never OOB
    if ((unsigned)sn1 >= N_NODES) sn1 = node;
    float v0[8], v1[8];
    gather(sn0, v0); gather(sn1, v1);
    process(v0); process(v1);
  }
  if (i < end) {
    int sn0 = esrc[i];
    if ((unsigned)sn0 >= N_NODES) sn0 = node;
    float v0[8]; gather(sn0, v0); process(v0);
  }

  float inv = (s > 0.f) ? 1.f / s : 0.f;        // defensive: no 0/0 NaN
  const int ln = tid >> 3;
#pragma unroll
  for (int c = 0; c < 8; ++c) {
    float v = fmaf(acc[c], inv, b1[h * C1 + c]);
    v = (v > 0.f) ? v : expm1f(v);    // ELU
    hsh[ln][h * 8 + c] = v;           // fp32 (no fp16 round-trip)
  }
  __syncthreads();                    // h ready + W2 staged

  // ---- phase 2: (ln, g) computes outputs g*6..g*6+5 of the 48-wide GEMM
  const int g = tid & 7;
  float a6[6] = {0.f, 0.f, 0.f, 0.f, 0.f, 0.f};
#pragma unroll 4
  for (int k = 0; k < 64; ++k) {
    float hv = hsh[ln][k];
    const float* wr = &w[k][g * 6];
#pragma unroll
    for (int j = 0; j < 6; ++j) a6[j] = fmaf(hv, wr[j], a6[j]);
  }
#pragma unroll
  for (int j = 0; j < 6; ++j) out48[ln][g * 6 + j] = a6[j];
  __syncthreads();

  // ---- repack: lane h packs node ln's head-h outputs
  const int gnode = blockIdx.x * 32 + ln;
  f16x4 hx;
#pragma unroll
  for (int c = 0; c < 3; ++c) hx[c] = (_Float16)out48[ln][h * 3 + c];
  hx[3] = (_Float16)0.f;
  *(f16x4*)(xl2p + (size_t)gnode * 32 + h * 4) = hx;
#pragma unroll
  for (int c = 0; c < 3; ++c)
    xr2[(size_t)gnode * HC2 + h * 3 + c] = out48[ln][24 + h * 3 + c];
}

// ---------------- layer-2 edge pass + head-mean + final softmax --------------
__global__ __launch_bounds__(256) void k_edge2(const _Float16* __restrict__ xl2p,
    const float* __restrict__ xr2, const float* __restrict__ att2,
    const float* __restrict__ b2, const int* __restrict__ rowptr,
    const int* __restrict__ esrc, float* __restrict__ out) {
  int t = blockIdx.x * blockDim.x + threadIdx.x;   // exact grid: N*8
  int node = t >> 3, h = t & 7;
  float xrv[3], av[3];
#pragma unroll
  for (int c = 0; c < 3; ++c) {
    xrv[c] = xr2[(size_t)node * HC2 + h * NCLS + c];
    av[c]  = att2[h * NCLS + c];
  }
  float m = -INFINITY, s = 0.f;
  float acc[3] = {0.f, 0.f, 0.f};

  auto process = [&](const float* v) {
    float logit = 0.f;
#pragma unroll
    for (int c = 0; c < 3; ++c) {
      float u = v[c] + xrv[c];
      u = (u > 0.f) ? u : NEG * u;
      logit = fmaf(u, av[c], logit);
    }
    float mn = fmaxf(m, logit);
    float so = __expf(m - mn);
    float p  = __expf(logit - mn);
    s = s * so + p;
#pragma unroll
    for (int c = 0; c < 3; ++c) acc[c] = fmaf(acc[c], so, p * v[c]);
    m = mn;
  };

  int beg = rowptr[node], end = rowptr[node + 1];
  int i = beg;
  for (; i + 1 < end; i += 2) {
    int sn0 = esrc[i], sn1 = esrc[i + 1];
    if ((unsigned)sn0 >= N_NODES) sn0 = node;
    if ((unsigned)sn1 >= N_NODES) sn1 = node;
    f16x4 q0 = *(const f16x4*)(xl2p + (size_t)sn0 * 32 + h * 4);  // 8B
    f16x4 q1 = *(const f16x4*)(xl2p + (size_t)sn1 * 32 + h * 4);
    float v0[3] = {(float)q0[0], (float)q0[1], (float)q0[2]};
    float v1[3] = {(float)q1[0], (float)q1[1], (float)q1[2]};
    process(v0); process(v1);
  }
  if (i < end) {
    int sn0 = esrc[i];
    if ((unsigned)sn0 >= N_NODES) sn0 = node;
    f16x4 q0 = *(const f16x4*)(xl2p + (size_t)sn0 * 32 + h * 4);
    float v0[3] = {(float)q0[0], (float)q0[1], (float)q0[2]};
    process(v0);
  }

  float inv = (s > 0.f) ? 1.f / s : 0.f;
  float o[3];
#pragma unroll
  for (int c = 0; c < 3; ++c) o[c] = acc[c] * inv;
  // mean over 8 heads (8-lane group butterfly; grid exact so all lanes live)
#pragma unroll
  for (int off = 1; off < 8; off <<= 1) {
#pragma unroll
    for (int c = 0; c < 3; ++c) o[c] += __shfl_xor(o[c], off);
  }
  if (h < 3) {
    float z[3];
#pragma unroll
    for (int c = 0; c < 3; ++c) z[c] = o[c] * 0.125f + b2[c];
    float mx = fmaxf(fmaxf(z[0], z[1]), z[2]);
    float e0 = __expf(z[0] - mx), e1 = __expf(z[1] - mx), e2 = __expf(z[2] - mx);
    float sum = e0 + e1 + e2;
    float num = (h == 0) ? e0 : (h == 1) ? e1 : e2;
    out[(size_t)node * NCLS + h] = num / sum;
  }
}

// ---------------- launch -----------------------------------------------------
extern "C" void kernel_launch(void* const* d_in, const int* in_sizes, int n_in,
                              void* d_out, int out_size, void* d_ws, size_t ws_size,
                              hipStream_t stream) {
  (void)in_sizes; (void)n_in; (void)out_size; (void)ws_size;
  const float* x    = (const float*)d_in[0];
  const int*   ei   = (const int*)d_in[1];
  const float* W1l  = (const float*)d_in[2];
  const float* W1r  = (const float*)d_in[3];
  const float* att1 = (const float*)d_in[4];
  const float* b1   = (const float*)d_in[5];
  const float* W2l  = (const float*)d_in[6];
  const float* W2r  = (const float*)d_in[7];
  const float* att2 = (const float*)d_in[8];
  const float* b2   = (const float*)d_in[9];
  float* out = (float*)d_out;

  char* w = (char*)d_ws;
  _Float16* xl1h  = (_Float16*)(w);            // 12.8 MB (bstage overlays pre-gemm1)
  float* xr1      = (float*)(w + 12800000);    // 25.6 MB -> ends 38.4M
  _Float16* xl2p  = (_Float16*)(w + 38400000); // 6.4 MB  (disjoint from xl1h!)
  float* xr2      = (float*)(w + 44800000);    // 9.6 MB -> ends 54.4M
  _Float16* Wimg  = (_Float16*)(w + 64000000); // 128 KB
  unsigned* bstage = (unsigned*)(w);           // 6.8 MB, dead before gemm1
  char* ip = w + 76800000;
  int* rowptr = (int*)(ip);                    // 400,004 B
  int* cmat   = (int*)(ip + 400128);           // 425,984 B
  int* bbase  = (int*)(ip + 826112);           // 1,028 B
  int* esrc   = (int*)(ip + 827648);           // 6.8 MB

  k_cntA    <<<NCHUNK + 256, 256, 0, stream>>>(ei, cmat, W1l, W1r, Wimg);
  k_scanA   <<<1, NBUCK, 0, stream>>>(cmat, bbase, rowptr);
  k_grpA    <<<NCHUNK, 256, 0, stream>>>(ei, cmat, bbase, bstage);
  k_partB   <<<NBUCK, 256, 0, stream>>>(bstage, bbase, rowptr, esrc);
  k_gemm1   <<<NBLK, 512, 0, stream>>>(x, Wimg, xl1h, xr1);
  k_edge1g2 <<<N_NODES / 32, 256, 0, stream>>>(xl1h, xr1, att1, b1, W2l, W2r,
                                               rowptr, esrc, xl2p, xr2);
  k_edge2   <<<(N_NODES * HEADS) / 256, 256, 0, stream>>>(xl2p, xr2, att2, b2, rowptr, esrc, out);
}